// Round 3
// baseline (1466.008 us; speedup 1.0000x reference)
//
#include <hip/hip_runtime.h>
#include <math.h>

#define NPTS 2048
#define KNN 20
#define EPS_BN 1e-5f

// ============================================================
// xx[b][n] = sum_c x[b][c][n]^2
// ============================================================
__global__ __launch_bounds__(256) void xx_kernel(const float* __restrict__ xin,
                                                 long bstride,
                                                 float* __restrict__ xx, int C) {
    int b = blockIdx.y;
    int n = blockIdx.x * 256 + threadIdx.x;
    const float* xb = xin + (long)b * bstride;
    float s = 0.f;
    for (int c = 0; c < C; ++c) {
        float v = xb[(long)c * NPTS + n];
        s = fmaf(v, v, s);
    }
    xx[(long)b * NPTS + n] = s;
}

// ============================================================
// Pairwise distances + exact top-k (k=20 smallest, tie -> smaller col).
// Block: 8 rows x 2048 cols, 256 threads, acc 8x8 in regs.
// __launch_bounds__(256,3): VGPR cap ~170 (peak live ~110). Round-2's
// default heuristic capped at 64 VGPRs -> 263 MB/dispatch scratch spill.
// grid (NPTS/8, B)
// ============================================================
__global__ __launch_bounds__(256, 3) void dist_topk_kernel(const float* __restrict__ xin,
                                                           long bstride,
                                                           const float* __restrict__ xx,
                                                           int* __restrict__ idxout, int C) {
    __shared__ float dist_s[4 * NPTS];   // 32 KB
    int b = blockIdx.y;
    int n0 = blockIdx.x * 8;
    int tid = threadIdx.x;
    const float* xb = xin + (long)b * bstride;

    float acc[8][8];
#pragma unroll
    for (int r = 0; r < 8; ++r)
#pragma unroll
        for (int i = 0; i < 8; ++i) acc[r][i] = 0.f;

    for (int c = 0; c < C; ++c) {
        const float* row = xb + (long)c * NPTS;
        float xm[8];
#pragma unroll
        for (int i = 0; i < 8; ++i) xm[i] = row[tid + 256 * i];
#pragma unroll
        for (int r = 0; r < 8; ++r) {
            float xnv = row[n0 + r];  // wave-uniform -> scalar load
#pragma unroll
            for (int i = 0; i < 8; ++i) acc[r][i] = fmaf(xnv, xm[i], acc[r][i]);
        }
    }

    const float* xxb = xx + (long)b * NPTS;
    float xxm[8];
#pragma unroll
    for (int i = 0; i < 8; ++i) xxm[i] = xxb[tid + 256 * i];
    float xxn[8];
#pragma unroll
    for (int r = 0; r < 8; ++r) xxn[r] = xxb[n0 + r];  // uniform

    int wave = tid >> 6, lane = tid & 63;

    for (int p = 0; p < 2; ++p) {
        __syncthreads();  // prior phase's LDS use complete
#pragma unroll
        for (int r4 = 0; r4 < 4; ++r4) {
            int r = p * 4 + r4;
#pragma unroll
            for (int i = 0; i < 8; ++i)
                dist_s[r4 * NPTS + tid + 256 * i] = xxn[r] + xxm[i] - 2.f * acc[r][i];
        }
        __syncthreads();

        // -------- per-wave selection of row n0 + p*4 + wave --------
        int n = n0 + p * 4 + wave;
        float v[32];
#pragma unroll
        for (int i = 0; i < 32; ++i) v[i] = dist_s[wave * NPTS + lane + 64 * i];
        int* outp = idxout + ((long)b * NPTS + n) * KNN;

        // threshold: T = max over 32 pair-minima (pairs lane^1)
        float lm = v[0];
#pragma unroll
        for (int i = 1; i < 32; ++i) lm = fminf(lm, v[i]);
        float pm = fminf(lm, __shfl_xor(lm, 1, 64));
        float T = pm;
#pragma unroll
        for (int off = 2; off < 64; off <<= 1) T = fmaxf(T, __shfl_xor(T, off, 64));

        // compact candidates (v <= T) into reused row region of dist_s
        float* cand_v = dist_s + wave * NPTS;              // [0..511]
        int* cand_i = (int*)(dist_s + wave * NPTS) + 512;  // [512..1023]
        int base = 0;
#pragma unroll
        for (int i = 0; i < 32; ++i) {
            bool pred = v[i] <= T;
            unsigned long long mask = __ballot(pred);
            int prefix = __builtin_amdgcn_mbcnt_hi(
                (unsigned)(mask >> 32),
                __builtin_amdgcn_mbcnt_lo((unsigned)mask, 0));
            if (pred) {
                int pos = base + prefix;
                if (pos < 512) { cand_v[pos] = v[i]; cand_i[pos] = lane + 64 * i; }
            }
            base += (int)__popcll(mask);
        }
        int M = base;

        if (M > 512) {
            // exact fallback (rare): original slow path on v[32]
            for (int kk = 0; kk < KNN; ++kk) {
                float bv = v[0];
                int bi = 0;
#pragma unroll
                for (int i = 1; i < 32; ++i)
                    if (v[i] < bv) { bv = v[i]; bi = i; }
                int bm = lane + 64 * bi;
#pragma unroll
                for (int off = 32; off >= 1; off >>= 1) {
                    float ov = __shfl_xor(bv, off, 64);
                    int om = __shfl_xor(bm, off, 64);
                    if (ov < bv || (ov == bv && om < bm)) { bv = ov; bm = om; }
                }
                if (lane == 0) outp[kk] = bm;
#pragma unroll
                for (int i = 0; i < 32; ++i)
                    if (bm == lane + 64 * i) v[i] = 3.0e38f;
            }
        } else {
            // pad to multiple of 64
            for (int t = M + lane; t < ((M + 63) & ~63); t += 64) cand_v[t] = 3.0e38f;
            int S = (M + 63) >> 6;  // 1..8, wave-uniform
            float cv[8];
            int ci[8];
#pragma unroll
            for (int j = 0; j < 8; ++j) { cv[j] = 3.0e38f; ci[j] = 0; }
#pragma unroll
            for (int j = 0; j < 8; ++j)
                if (j < S) { cv[j] = cand_v[lane + 64 * j]; ci[j] = cand_i[lane + 64 * j]; }

            for (int kk = 0; kk < KNN; ++kk) {
                float bv = cv[0];
                int bi = ci[0];
                int bp = lane;  // pos = lane + 64*j; pos order == column order
#pragma unroll
                for (int j = 1; j < 8; ++j)
                    if (j < S) {
                        if (cv[j] < bv) { bv = cv[j]; bi = ci[j]; bp = lane + 64 * j; }
                    }
#pragma unroll
                for (int off = 32; off >= 1; off >>= 1) {
                    float ov = __shfl_xor(bv, off, 64);
                    int oi = __shfl_xor(bi, off, 64);
                    int opp = __shfl_xor(bp, off, 64);
                    if (ov < bv || (ov == bv && opp < bp)) { bv = ov; bi = oi; bp = opp; }
                }
                if (lane == 0) outp[kk] = bi;
                int j0 = bp >> 6, l0 = bp & 63;  // wave-uniform
#pragma unroll
                for (int j = 0; j < 8; ++j)
                    if (j == j0 && lane == l0) cv[j] = 3.0e38f;
            }
        }
    }
}

// ============================================================
// t' = bn_scale*(W1-W2)@x + bn_bias ; u' = bn_scale*W2@x
// Block: 16 o x 256 n, thread: 16 o x 1 n. grid (NPTS/256, O/16, B)
// ============================================================
__global__ __launch_bounds__(256) void gemm_tu_kernel(
    const float* __restrict__ xin, long bstride, const float* __restrict__ W,
    const float* __restrict__ bg, const float* __restrict__ bb,
    const float* __restrict__ bm, const float* __restrict__ bv,
    float* __restrict__ tbuf, float* __restrict__ ubuf, int C, int O) {
    __shared__ float wa_s[128 * 16];  // (W1-W2)[c][ol]
    __shared__ float wb_s[128 * 16];  // W2[c][ol]
    int b = blockIdx.z;
    int o0 = blockIdx.y * 16;
    int n0 = blockIdx.x * 256;
    int tid = threadIdx.x;

    for (int i = tid; i < C * 16; i += 256) {
        int c = i >> 4, ol = i & 15;
        float w1 = W[(long)(o0 + ol) * (2 * C) + c];
        float w2 = W[(long)(o0 + ol) * (2 * C) + C + c];
        wa_s[i] = w1 - w2;
        wb_s[i] = w2;
    }
    __syncthreads();

    float ta[16], ua[16];
#pragma unroll
    for (int ol = 0; ol < 16; ++ol) { ta[ol] = 0.f; ua[ol] = 0.f; }

    const float* xb = xin + (long)b * bstride;
    for (int c = 0; c < C; ++c) {
        float xv = xb[(long)c * NPTS + n0 + tid];
        const float* wac = wa_s + c * 16;
        const float* wbc = wb_s + c * 16;
#pragma unroll
        for (int ol = 0; ol < 16; ++ol) {
            ta[ol] = fmaf(wac[ol], xv, ta[ol]);
            ua[ol] = fmaf(wbc[ol], xv, ua[ol]);
        }
    }

#pragma unroll
    for (int ol = 0; ol < 16; ++ol) {
        int o = o0 + ol;
        float sc = bg[o] / sqrtf(bv[o] + EPS_BN);
        float bias = bb[o] - bm[o] * sc;
        long base = ((long)b * O + o) * NPTS + n0 + tid;
        tbuf[base] = ta[ol] * sc + bias;
        ubuf[base] = ua[ol] * sc;
    }
}

// ============================================================
// out[b][o][n] = max_j lrelu(t'[b][o][n] + u'[b][o][idx[b][n][j]])
// grid (O, 2, B); block stages u' row in LDS, processes 1024 n (4/thread)
// ============================================================
__global__ __launch_bounds__(256) void gather_kernel(const float* __restrict__ tbuf,
                                                     const float* __restrict__ ubuf,
                                                     const int* __restrict__ idx,
                                                     float* __restrict__ out, int O) {
    __shared__ float urow[NPTS];
    int o = blockIdx.x, half = blockIdx.y, b = blockIdx.z;
    int tid = threadIdx.x;
    const float4* up4 = (const float4*)(ubuf + ((long)b * O + o) * NPTS);
    float4* ur4 = (float4*)urow;
    for (int i = tid; i < NPTS / 4; i += 256) ur4[i] = up4[i];
    __syncthreads();

    const float* tp = tbuf + ((long)b * O + o) * NPTS;
    float* op = out + (long)b * (512 * NPTS) + (long)o * NPTS;
    int n = half * 1024 + tid * 4;
    float4 tv4 = *(const float4*)(tp + n);
    float tv[4] = {tv4.x, tv4.y, tv4.z, tv4.w};
    float res[4];
#pragma unroll
    for (int q = 0; q < 4; ++q) {
        const int4* ip = (const int4*)(idx + ((long)b * NPTS + n + q) * KNN);
        float mx = -3.0e38f;
#pragma unroll
        for (int jj = 0; jj < 5; ++jj) {
            int4 i4 = ip[jj];
            float y0 = tv[q] + urow[i4.x];
            float y1 = tv[q] + urow[i4.y];
            float y2 = tv[q] + urow[i4.z];
            float y3 = tv[q] + urow[i4.w];
            y0 = y0 > 0.f ? y0 : 0.2f * y0;
            y1 = y1 > 0.f ? y1 : 0.2f * y1;
            y2 = y2 > 0.f ? y2 : 0.2f * y2;
            y3 = y3 > 0.f ? y3 : 0.2f * y3;
            mx = fmaxf(mx, fmaxf(fmaxf(y0, y1), fmaxf(y2, y3)));
        }
        res[q] = mx;
    }
    *(float4*)(op + n) = make_float4(res[0], res[1], res[2], res[3]);
}

// ============================================================
// emb = lrelu(bn5(W5 @ xc)); partial max/sum over n-half.
// __launch_bounds__(256,3): keep acc[4][16] in VGPRs (round-2 default
// allocated 60 VGPRs -> accumulators bounced through AGPR/scratch).
// grid (1024/16, 2, B)
// ============================================================
__global__ __launch_bounds__(256, 3) void w5_reduce_kernel(
    const float* __restrict__ xc, const float* __restrict__ W5,
    const float* __restrict__ bg, const float* __restrict__ bb,
    const float* __restrict__ bm, const float* __restrict__ bv,
    float* __restrict__ pmax, float* __restrict__ psum) {
    __shared__ float w_s[512 * 16];  // 32 KB, [c][ol]
    __shared__ float rmax[4][16];
    __shared__ float rsum[4][16];
    int b = blockIdx.z;
    int half = blockIdx.y;
    int o0 = blockIdx.x * 16;
    int tid = threadIdx.x;

    for (int i = tid; i < 512 * 16; i += 256) {
        int c = i >> 4, ol = i & 15;
        w_s[i] = W5[(long)(o0 + ol) * 512 + c];
    }
    __syncthreads();

    float acc[4][16];
#pragma unroll
    for (int v = 0; v < 4; ++v)
#pragma unroll
        for (int ol = 0; ol < 16; ++ol) acc[v][ol] = 0.f;

    const float* xb = xc + (long)b * 512 * NPTS + half * 1024;
    for (int c = 0; c < 512; ++c) {
        const float* row = xb + (long)c * NPTS;
        float xv0 = row[tid];
        float xv1 = row[tid + 256];
        float xv2 = row[tid + 512];
        float xv3 = row[tid + 768];
        const float* wc = w_s + c * 16;
#pragma unroll
        for (int ol = 0; ol < 16; ++ol) {
            float w = wc[ol];
            acc[0][ol] = fmaf(w, xv0, acc[0][ol]);
            acc[1][ol] = fmaf(w, xv1, acc[1][ol]);
            acc[2][ol] = fmaf(w, xv2, acc[2][ol]);
            acc[3][ol] = fmaf(w, xv3, acc[3][ol]);
        }
    }

    float mx[16], sm[16];
#pragma unroll
    for (int ol = 0; ol < 16; ++ol) {
        int o = o0 + ol;
        float sc = bg[o] / sqrtf(bv[o] + EPS_BN);
        float bi = bb[o] - bm[o] * sc;
        float m = -3.0e38f, s = 0.f;
#pragma unroll
        for (int v = 0; v < 4; ++v) {
            float y = acc[v][ol] * sc + bi;
            y = y > 0.f ? y : 0.2f * y;
            m = fmaxf(m, y);
            s += y;
        }
        mx[ol] = m;
        sm[ol] = s;
    }

    int wave = tid >> 6, lane = tid & 63;
#pragma unroll
    for (int ol = 0; ol < 16; ++ol) {
        float m = mx[ol], s = sm[ol];
#pragma unroll
        for (int off = 32; off >= 1; off >>= 1) {
            m = fmaxf(m, __shfl_xor(m, off, 64));
            s += __shfl_xor(s, off, 64);
        }
        mx[ol] = m;
        sm[ol] = s;
    }
    if (lane == 0) {
#pragma unroll
        for (int ol = 0; ol < 16; ++ol) { rmax[wave][ol] = mx[ol]; rsum[wave][ol] = sm[ol]; }
    }
    __syncthreads();
    if (tid < 16) {
        float m = rmax[0][tid], s = rsum[0][tid];
#pragma unroll
        for (int w = 1; w < 4; ++w) { m = fmaxf(m, rmax[w][tid]); s += rsum[w][tid]; }
        long base = ((long)half * 8 + b) * 1024 + o0 + tid;
        pmax[base] = m;
        psum[base] = s;
    }
}

// combine halves -> feat[b][0..1023]=max, feat[b][1024..2047]=mean
__global__ __launch_bounds__(256) void w5_combine_kernel(const float* __restrict__ pmax,
                                                         const float* __restrict__ psum,
                                                         float* __restrict__ feat) {
    int b = blockIdx.x;
    for (int o = threadIdx.x; o < 1024; o += 256) {
        float m = fmaxf(pmax[(long)b * 1024 + o], pmax[(long)(8 + b) * 1024 + o]);
        float s = psum[(long)b * 1024 + o] + psum[(long)(8 + b) * 1024 + o];
        feat[(long)b * 2048 + o] = m;
        feat[(long)b * 2048 + 1024 + o] = s * (1.f / 2048.f);
    }
}

// ============================================================
// Generic FC: out[b][o] = act(bn(in[b] . W[o]))  (wave per o)
// ============================================================
__global__ __launch_bounds__(256) void fc_kernel(const float* __restrict__ in,
                                                 const float* __restrict__ W,
                                                 const float* __restrict__ bg,
                                                 const float* __restrict__ bb,
                                                 const float* __restrict__ bm,
                                                 const float* __restrict__ bv,
                                                 float* __restrict__ out, int I, int O,
                                                 int do_lrelu) {
    int b = blockIdx.y;
    int o = blockIdx.x * 4 + (threadIdx.x >> 6);
    int lane = threadIdx.x & 63;
    if (o < O) {
        const float* ip = in + (long)b * I;
        const float* wp = W + (long)o * I;
        float s = 0.f;
        for (int i = lane; i < I; i += 64) s = fmaf(ip[i], wp[i], s);
#pragma unroll
        for (int off = 32; off >= 1; off >>= 1) s += __shfl_xor(s, off, 64);
        if (lane == 0) {
            float y;
            if (bg) {
                float scv = bg[o] / sqrtf(bv[o] + EPS_BN);
                y = (s - bm[o]) * scv + bb[o];
                if (do_lrelu) y = y > 0.f ? y : 0.2f * y;
            } else {
                y = s + bb[o];
            }
            out[(long)b * O + o] = y;
        }
    }
}

// ============================================================
extern "C" void kernel_launch(void* const* d_in, const int* in_sizes, int n_in,
                              void* d_out, int out_size, void* d_ws, size_t ws_size,
                              hipStream_t stream) {
    const float* x = (const float*)d_in[0];
    const float* W1 = (const float*)d_in[1];
    const float* W2 = (const float*)d_in[6];
    const float* W3 = (const float*)d_in[11];
    const float* W4 = (const float*)d_in[16];
    const float* W5 = (const float*)d_in[21];
    const float* L1 = (const float*)d_in[26];
    const float* L2 = (const float*)d_in[31];
    const float* L3 = (const float*)d_in[36];
    const float* L3b = (const float*)d_in[37];

    // workspace layout
    float* xc = (float*)d_ws;                         // 8*512*2048
    float* tb = xc + (long)8 * 512 * NPTS;            // 8*256*2048
    float* ub = tb + (long)8 * 256 * NPTS;            // 8*256*2048
    int* idx = (int*)(ub + (long)8 * 256 * NPTS);     // 8*2048*20
    float* xxb = (float*)(idx + (long)8 * NPTS * KNN);  // 8*2048
    float* feat = xxb + (long)8 * NPTS;               // 8*2048
    float* h1 = feat + (long)8 * NPTS;                // 8*512
    float* h2 = h1 + (long)8 * 512;                   // 8*256
    // pmax/psum reuse tb region (tb/ub dead after layer-4 gather)
    float* pmax = tb;                                 // 2*8*1024
    float* psum = tb + (long)2 * 8 * 1024;            // 2*8*1024

    struct Layer {
        const float* xin; long bstride; const float* W;
        const float *g, *b, *m, *v; int C, O, c0;
    };
    Layer layers[4] = {
        {x, (long)3 * NPTS, W1,
         (const float*)d_in[2], (const float*)d_in[3], (const float*)d_in[4], (const float*)d_in[5],
         3, 64, 0},
        {xc, (long)512 * NPTS, W2,
         (const float*)d_in[7], (const float*)d_in[8], (const float*)d_in[9], (const float*)d_in[10],
         64, 64, 64},
        {xc + (long)64 * NPTS, (long)512 * NPTS, W3,
         (const float*)d_in[12], (const float*)d_in[13], (const float*)d_in[14], (const float*)d_in[15],
         64, 128, 128},
        {xc + (long)128 * NPTS, (long)512 * NPTS, W4,
         (const float*)d_in[17], (const float*)d_in[18], (const float*)d_in[19], (const float*)d_in[20],
         128, 256, 256},
    };

    for (int l = 0; l < 4; ++l) {
        const Layer& L = layers[l];
        xx_kernel<<<dim3(NPTS / 256, 8), 256, 0, stream>>>(L.xin, L.bstride, xxb, L.C);
        dist_topk_kernel<<<dim3(NPTS / 8, 8), 256, 0, stream>>>(L.xin, L.bstride, xxb, idx, L.C);
        gemm_tu_kernel<<<dim3(NPTS / 256, L.O / 16, 8), 256, 0, stream>>>(
            L.xin, L.bstride, L.W, L.g, L.b, L.m, L.v, tb, ub, L.C, L.O);
        gather_kernel<<<dim3(L.O, 2, 8), 256, 0, stream>>>(tb, ub, idx, xc + (long)L.c0 * NPTS, L.O);
    }

    w5_reduce_kernel<<<dim3(1024 / 16, 2, 8), 256, 0, stream>>>(
        xc, W5, (const float*)d_in[22], (const float*)d_in[23], (const float*)d_in[24],
        (const float*)d_in[25], pmax, psum);
    w5_combine_kernel<<<dim3(8), 256, 0, stream>>>(pmax, psum, feat);

    fc_kernel<<<dim3(512 / 4, 8), 256, 0, stream>>>(
        feat, L1, (const float*)d_in[27], (const float*)d_in[28], (const float*)d_in[29],
        (const float*)d_in[30], h1, 2048, 512, 1);
    fc_kernel<<<dim3(256 / 4, 8), 256, 0, stream>>>(
        h1, L2, (const float*)d_in[32], (const float*)d_in[33], (const float*)d_in[34],
        (const float*)d_in[35], h2, 512, 256, 1);
    fc_kernel<<<dim3(10, 8), 256, 0, stream>>>(
        h2, L3, nullptr, L3b, nullptr, nullptr, (float*)d_out, 256, 40, 0);
}

// Round 4
// 1287.176 us; speedup vs baseline: 1.1389x; 1.1389x over previous
//
#include <hip/hip_runtime.h>
#include <math.h>

#define NPTS 2048
#define KNN 20
#define EPS_BN 1e-5f

// ============================================================
// xx[b][n] = sum_c x[b][c][n]^2
// ============================================================
__global__ __launch_bounds__(256) void xx_kernel(const float* __restrict__ xin,
                                                 long bstride,
                                                 float* __restrict__ xx, int C) {
    int b = blockIdx.y;
    int n = blockIdx.x * 256 + threadIdx.x;
    const float* xb = xin + (long)b * bstride;
    float s = 0.f;
    for (int c = 0; c < C; ++c) {
        float v = xb[(long)c * NPTS + n];
        s = fmaf(v, v, s);
    }
    xx[(long)b * NPTS + n] = s;
}

// ============================================================
// Pairwise distances + exact top-k (k=20 smallest, tie -> smaller col).
// 512 threads. Block: 8 rows x 2048 cols; thread: 8 rows x 4 cols
// (acc[8][4]=32 regs -- rounds 2/3 used acc[8][8]=64 which the
// allocator refused to house -> 280 MB/dispatch scratch spill).
// dist_s = 8 x 2048 = 64 KB LDS; selection: wave w owns row w.
// grid (NPTS/8, B)
// ============================================================
__global__ __launch_bounds__(512) void dist_topk_kernel(const float* __restrict__ xin,
                                                        long bstride,
                                                        const float* __restrict__ xx,
                                                        int* __restrict__ idxout, int C) {
    __shared__ float dist_s[8 * NPTS];   // 64 KB
    int b = blockIdx.y;
    int n0 = blockIdx.x * 8;
    int tid = threadIdx.x;               // 0..511
    const float* xb = xin + (long)b * bstride;

    float acc[8][4];
#pragma unroll
    for (int r = 0; r < 8; ++r)
#pragma unroll
        for (int q = 0; q < 4; ++q) acc[r][q] = 0.f;

    for (int c = 0; c < C; ++c) {
        const float* row = xb + (long)c * NPTS;
        float4 xm4 = *(const float4*)(row + 4 * tid);  // cols 4tid..4tid+3
        float xm[4] = {xm4.x, xm4.y, xm4.z, xm4.w};
#pragma unroll
        for (int r = 0; r < 8; ++r) {
            float xnv = row[n0 + r];  // block-uniform -> scalar load
#pragma unroll
            for (int q = 0; q < 4; ++q) acc[r][q] = fmaf(xnv, xm[q], acc[r][q]);
        }
    }

    const float* xxb = xx + (long)b * NPTS;
    float4 xxm4 = *(const float4*)(xxb + 4 * tid);
    float xxm[4] = {xxm4.x, xxm4.y, xxm4.z, xxm4.w};
    float xxn[8];
#pragma unroll
    for (int r = 0; r < 8; ++r) xxn[r] = xxb[n0 + r];  // uniform

#pragma unroll
    for (int r = 0; r < 8; ++r) {
        float4 d;
        d.x = xxn[r] + xxm[0] - 2.f * acc[r][0];
        d.y = xxn[r] + xxm[1] - 2.f * acc[r][1];
        d.z = xxn[r] + xxm[2] - 2.f * acc[r][2];
        d.w = xxn[r] + xxm[3] - 2.f * acc[r][3];
        *(float4*)(dist_s + r * NPTS + 4 * tid) = d;
    }
    __syncthreads();

    // -------- per-wave selection: wave w owns row n0 + w --------
    int wave = tid >> 6, lane = tid & 63;
    int n = n0 + wave;
    float v[32];
#pragma unroll
    for (int i = 0; i < 32; ++i) v[i] = dist_s[wave * NPTS + lane + 64 * i];
    int* outp = idxout + ((long)b * NPTS + n) * KNN;

    // threshold: T = max over 32 pair-minima (pairs lane^1) -> >=32 cands <= T
    float lm = v[0];
#pragma unroll
    for (int i = 1; i < 32; ++i) lm = fminf(lm, v[i]);
    float pm = fminf(lm, __shfl_xor(lm, 1, 64));
    float T = pm;
#pragma unroll
    for (int off = 2; off < 64; off <<= 1) T = fmaxf(T, __shfl_xor(T, off, 64));

    // compact candidates (v <= T) into this wave's (dead) dist row
    float* cand_v = dist_s + wave * NPTS;              // [0..511]
    int* cand_i = (int*)(dist_s + wave * NPTS) + 512;  // [512..1023]
    int base = 0;
#pragma unroll
    for (int i = 0; i < 32; ++i) {
        bool pred = v[i] <= T;
        unsigned long long mask = __ballot(pred);
        int prefix = __builtin_amdgcn_mbcnt_hi(
            (unsigned)(mask >> 32),
            __builtin_amdgcn_mbcnt_lo((unsigned)mask, 0));
        if (pred) {
            int pos = base + prefix;
            if (pos < 512) { cand_v[pos] = v[i]; cand_i[pos] = lane + 64 * i; }
        }
        base += (int)__popcll(mask);
    }
    int M = base;

    if (M > 512) {
        // exact fallback (rare): slow path on v[32]
        for (int kk = 0; kk < KNN; ++kk) {
            float bv = v[0];
            int bi = 0;
#pragma unroll
            for (int i = 1; i < 32; ++i)
                if (v[i] < bv) { bv = v[i]; bi = i; }
            int bm = lane + 64 * bi;
#pragma unroll
            for (int off = 32; off >= 1; off >>= 1) {
                float ov = __shfl_xor(bv, off, 64);
                int om = __shfl_xor(bm, off, 64);
                if (ov < bv || (ov == bv && om < bm)) { bv = ov; bm = om; }
            }
            if (lane == 0) outp[kk] = bm;
#pragma unroll
            for (int i = 0; i < 32; ++i)
                if (bm == lane + 64 * i) v[i] = 3.0e38f;
        }
    } else {
        // pad to multiple of 64
        for (int t = M + lane; t < ((M + 63) & ~63); t += 64) cand_v[t] = 3.0e38f;
        int S = (M + 63) >> 6;  // 1..8, wave-uniform
        float cv[8];
        int ci[8];
#pragma unroll
        for (int j = 0; j < 8; ++j) { cv[j] = 3.0e38f; ci[j] = 0; }
#pragma unroll
        for (int j = 0; j < 8; ++j)
            if (j < S) { cv[j] = cand_v[lane + 64 * j]; ci[j] = cand_i[lane + 64 * j]; }

        for (int kk = 0; kk < KNN; ++kk) {
            float bv = cv[0];
            int bi = ci[0];
            int bp = lane;  // pos = lane + 64*j; pos order == column order
#pragma unroll
            for (int j = 1; j < 8; ++j)
                if (j < S) {
                    if (cv[j] < bv) { bv = cv[j]; bi = ci[j]; bp = lane + 64 * j; }
                }
#pragma unroll
            for (int off = 32; off >= 1; off >>= 1) {
                float ov = __shfl_xor(bv, off, 64);
                int oi = __shfl_xor(bi, off, 64);
                int opp = __shfl_xor(bp, off, 64);
                if (ov < bv || (ov == bv && opp < bp)) { bv = ov; bi = oi; bp = opp; }
            }
            if (lane == 0) outp[kk] = bi;
            int j0 = bp >> 6, l0 = bp & 63;  // wave-uniform
#pragma unroll
            for (int j = 0; j < 8; ++j)
                if (j == j0 && lane == l0) cv[j] = 3.0e38f;
        }
    }
}

// ============================================================
// t' = bn_scale*(W1-W2)@x + bn_bias ; u' = bn_scale*W2@x
// Block: 16 o x 256 n, thread: 16 o x 1 n. grid (NPTS/256, O/16, B)
// ============================================================
__global__ __launch_bounds__(256) void gemm_tu_kernel(
    const float* __restrict__ xin, long bstride, const float* __restrict__ W,
    const float* __restrict__ bg, const float* __restrict__ bb,
    const float* __restrict__ bm, const float* __restrict__ bv,
    float* __restrict__ tbuf, float* __restrict__ ubuf, int C, int O) {
    __shared__ float wa_s[128 * 16];  // (W1-W2)[c][ol]
    __shared__ float wb_s[128 * 16];  // W2[c][ol]
    int b = blockIdx.z;
    int o0 = blockIdx.y * 16;
    int n0 = blockIdx.x * 256;
    int tid = threadIdx.x;

    for (int i = tid; i < C * 16; i += 256) {
        int c = i >> 4, ol = i & 15;
        float w1 = W[(long)(o0 + ol) * (2 * C) + c];
        float w2 = W[(long)(o0 + ol) * (2 * C) + C + c];
        wa_s[i] = w1 - w2;
        wb_s[i] = w2;
    }
    __syncthreads();

    float ta[16], ua[16];
#pragma unroll
    for (int ol = 0; ol < 16; ++ol) { ta[ol] = 0.f; ua[ol] = 0.f; }

    const float* xb = xin + (long)b * bstride;
    for (int c = 0; c < C; ++c) {
        float xv = xb[(long)c * NPTS + n0 + tid];
        const float* wac = wa_s + c * 16;
        const float* wbc = wb_s + c * 16;
#pragma unroll
        for (int ol = 0; ol < 16; ++ol) {
            ta[ol] = fmaf(wac[ol], xv, ta[ol]);
            ua[ol] = fmaf(wbc[ol], xv, ua[ol]);
        }
    }

#pragma unroll
    for (int ol = 0; ol < 16; ++ol) {
        int o = o0 + ol;
        float sc = bg[o] / sqrtf(bv[o] + EPS_BN);
        float bias = bb[o] - bm[o] * sc;
        long base = ((long)b * O + o) * NPTS + n0 + tid;
        tbuf[base] = ta[ol] * sc + bias;
        ubuf[base] = ua[ol] * sc;
    }
}

// ============================================================
// out[b][o][n] = max_j lrelu(t'[b][o][n] + u'[b][o][idx[b][n][j]])
// grid (O, 2, B); block stages u' row in LDS, processes 1024 n (4/thread)
// ============================================================
__global__ __launch_bounds__(256) void gather_kernel(const float* __restrict__ tbuf,
                                                     const float* __restrict__ ubuf,
                                                     const int* __restrict__ idx,
                                                     float* __restrict__ out, int O) {
    __shared__ float urow[NPTS];
    int o = blockIdx.x, half = blockIdx.y, b = blockIdx.z;
    int tid = threadIdx.x;
    const float4* up4 = (const float4*)(ubuf + ((long)b * O + o) * NPTS);
    float4* ur4 = (float4*)urow;
    for (int i = tid; i < NPTS / 4; i += 256) ur4[i] = up4[i];
    __syncthreads();

    const float* tp = tbuf + ((long)b * O + o) * NPTS;
    float* op = out + (long)b * (512 * NPTS) + (long)o * NPTS;
    int n = half * 1024 + tid * 4;
    float4 tv4 = *(const float4*)(tp + n);
    float tv[4] = {tv4.x, tv4.y, tv4.z, tv4.w};
    float res[4];
#pragma unroll
    for (int q = 0; q < 4; ++q) {
        const int4* ip = (const int4*)(idx + ((long)b * NPTS + n + q) * KNN);
        float mx = -3.0e38f;
#pragma unroll
        for (int jj = 0; jj < 5; ++jj) {
            int4 i4 = ip[jj];
            float y0 = tv[q] + urow[i4.x];
            float y1 = tv[q] + urow[i4.y];
            float y2 = tv[q] + urow[i4.z];
            float y3 = tv[q] + urow[i4.w];
            y0 = y0 > 0.f ? y0 : 0.2f * y0;
            y1 = y1 > 0.f ? y1 : 0.2f * y1;
            y2 = y2 > 0.f ? y2 : 0.2f * y2;
            y3 = y3 > 0.f ? y3 : 0.2f * y3;
            mx = fmaxf(mx, fmaxf(fmaxf(y0, y1), fmaxf(y2, y3)));
        }
        res[q] = mx;
    }
    *(float4*)(op + n) = make_float4(res[0], res[1], res[2], res[3]);
}

// ============================================================
// emb = lrelu(bn5(W5 @ xc)); partial max/sum over n-half.
// 512 threads. Block: 16 o x 1024 cols; thread: 16 o x 2 cols
// (acc[2][16]=32 regs -- previous acc[4][16]=64 spilled/AGPR-bounced).
// grid (1024/16, 2, B)
// ============================================================
__global__ __launch_bounds__(512) void w5_reduce_kernel(
    const float* __restrict__ xc, const float* __restrict__ W5,
    const float* __restrict__ bg, const float* __restrict__ bb,
    const float* __restrict__ bm, const float* __restrict__ bv,
    float* __restrict__ pmax, float* __restrict__ psum) {
    __shared__ float w_s[512 * 16];  // 32 KB, [c][ol]
    __shared__ float rmax[8][16];
    __shared__ float rsum[8][16];
    int b = blockIdx.z;
    int half = blockIdx.y;
    int o0 = blockIdx.x * 16;
    int tid = threadIdx.x;  // 0..511

    for (int i = tid; i < 512 * 16; i += 512) {
        int c = i >> 4, ol = i & 15;
        w_s[i] = W5[(long)(o0 + ol) * 512 + c];
    }
    __syncthreads();

    float acc[2][16];
#pragma unroll
    for (int v = 0; v < 2; ++v)
#pragma unroll
        for (int ol = 0; ol < 16; ++ol) acc[v][ol] = 0.f;

    const float* xb = xc + (long)b * 512 * NPTS + half * 1024;
    for (int c = 0; c < 512; ++c) {
        float2 xv = *(const float2*)(xb + (long)c * NPTS + 2 * tid);
        const float* wc = w_s + c * 16;
#pragma unroll
        for (int ol = 0; ol < 16; ++ol) {
            float w = wc[ol];
            acc[0][ol] = fmaf(w, xv.x, acc[0][ol]);
            acc[1][ol] = fmaf(w, xv.y, acc[1][ol]);
        }
    }

    float mx[16], sm[16];
#pragma unroll
    for (int ol = 0; ol < 16; ++ol) {
        int o = o0 + ol;
        float sc = bg[o] / sqrtf(bv[o] + EPS_BN);
        float bi = bb[o] - bm[o] * sc;
        float y0 = acc[0][ol] * sc + bi;
        float y1 = acc[1][ol] * sc + bi;
        y0 = y0 > 0.f ? y0 : 0.2f * y0;
        y1 = y1 > 0.f ? y1 : 0.2f * y1;
        mx[ol] = fmaxf(y0, y1);
        sm[ol] = y0 + y1;
    }

    int wave = tid >> 6, lane = tid & 63;
#pragma unroll
    for (int ol = 0; ol < 16; ++ol) {
        float m = mx[ol], s = sm[ol];
#pragma unroll
        for (int off = 32; off >= 1; off >>= 1) {
            m = fmaxf(m, __shfl_xor(m, off, 64));
            s += __shfl_xor(s, off, 64);
        }
        mx[ol] = m;
        sm[ol] = s;
    }
    if (lane == 0) {
#pragma unroll
        for (int ol = 0; ol < 16; ++ol) { rmax[wave][ol] = mx[ol]; rsum[wave][ol] = sm[ol]; }
    }
    __syncthreads();
    if (tid < 16) {
        float m = rmax[0][tid], s = rsum[0][tid];
#pragma unroll
        for (int w = 1; w < 8; ++w) { m = fmaxf(m, rmax[w][tid]); s += rsum[w][tid]; }
        long base = ((long)half * 8 + b) * 1024 + o0 + tid;
        pmax[base] = m;
        psum[base] = s;
    }
}

// combine halves -> feat[b][0..1023]=max, feat[b][1024..2047]=mean
__global__ __launch_bounds__(256) void w5_combine_kernel(const float* __restrict__ pmax,
                                                         const float* __restrict__ psum,
                                                         float* __restrict__ feat) {
    int b = blockIdx.x;
    for (int o = threadIdx.x; o < 1024; o += 256) {
        float m = fmaxf(pmax[(long)b * 1024 + o], pmax[(long)(8 + b) * 1024 + o]);
        float s = psum[(long)b * 1024 + o] + psum[(long)(8 + b) * 1024 + o];
        feat[(long)b * 2048 + o] = m;
        feat[(long)b * 2048 + 1024 + o] = s * (1.f / 2048.f);
    }
}

// ============================================================
// Generic FC: out[b][o] = act(bn(in[b] . W[o]))  (wave per o)
// ============================================================
__global__ __launch_bounds__(256) void fc_kernel(const float* __restrict__ in,
                                                 const float* __restrict__ W,
                                                 const float* __restrict__ bg,
                                                 const float* __restrict__ bb,
                                                 const float* __restrict__ bm,
                                                 const float* __restrict__ bv,
                                                 float* __restrict__ out, int I, int O,
                                                 int do_lrelu) {
    int b = blockIdx.y;
    int o = blockIdx.x * 4 + (threadIdx.x >> 6);
    int lane = threadIdx.x & 63;
    if (o < O) {
        const float* ip = in + (long)b * I;
        const float* wp = W + (long)o * I;
        float s = 0.f;
        for (int i = lane; i < I; i += 64) s = fmaf(ip[i], wp[i], s);
#pragma unroll
        for (int off = 32; off >= 1; off >>= 1) s += __shfl_xor(s, off, 64);
        if (lane == 0) {
            float y;
            if (bg) {
                float scv = bg[o] / sqrtf(bv[o] + EPS_BN);
                y = (s - bm[o]) * scv + bb[o];
                if (do_lrelu) y = y > 0.f ? y : 0.2f * y;
            } else {
                y = s + bb[o];
            }
            out[(long)b * O + o] = y;
        }
    }
}

// ============================================================
extern "C" void kernel_launch(void* const* d_in, const int* in_sizes, int n_in,
                              void* d_out, int out_size, void* d_ws, size_t ws_size,
                              hipStream_t stream) {
    const float* x = (const float*)d_in[0];
    const float* W1 = (const float*)d_in[1];
    const float* W2 = (const float*)d_in[6];
    const float* W3 = (const float*)d_in[11];
    const float* W4 = (const float*)d_in[16];
    const float* W5 = (const float*)d_in[21];
    const float* L1 = (const float*)d_in[26];
    const float* L2 = (const float*)d_in[31];
    const float* L3 = (const float*)d_in[36];
    const float* L3b = (const float*)d_in[37];

    // workspace layout
    float* xc = (float*)d_ws;                         // 8*512*2048
    float* tb = xc + (long)8 * 512 * NPTS;            // 8*256*2048
    float* ub = tb + (long)8 * 256 * NPTS;            // 8*256*2048
    int* idx = (int*)(ub + (long)8 * 256 * NPTS);     // 8*2048*20
    float* xxb = (float*)(idx + (long)8 * NPTS * KNN);  // 8*2048
    float* feat = xxb + (long)8 * NPTS;               // 8*2048
    float* h1 = feat + (long)8 * NPTS;                // 8*512
    float* h2 = h1 + (long)8 * 512;                   // 8*256
    // pmax/psum reuse tb region (tb/ub dead after layer-4 gather)
    float* pmax = tb;                                 // 2*8*1024
    float* psum = tb + (long)2 * 8 * 1024;            // 2*8*1024

    struct Layer {
        const float* xin; long bstride; const float* W;
        const float *g, *b, *m, *v; int C, O, c0;
    };
    Layer layers[4] = {
        {x, (long)3 * NPTS, W1,
         (const float*)d_in[2], (const float*)d_in[3], (const float*)d_in[4], (const float*)d_in[5],
         3, 64, 0},
        {xc, (long)512 * NPTS, W2,
         (const float*)d_in[7], (const float*)d_in[8], (const float*)d_in[9], (const float*)d_in[10],
         64, 64, 64},
        {xc + (long)64 * NPTS, (long)512 * NPTS, W3,
         (const float*)d_in[12], (const float*)d_in[13], (const float*)d_in[14], (const float*)d_in[15],
         64, 128, 128},
        {xc + (long)128 * NPTS, (long)512 * NPTS, W4,
         (const float*)d_in[17], (const float*)d_in[18], (const float*)d_in[19], (const float*)d_in[20],
         128, 256, 256},
    };

    for (int l = 0; l < 4; ++l) {
        const Layer& L = layers[l];
        xx_kernel<<<dim3(NPTS / 256, 8), 256, 0, stream>>>(L.xin, L.bstride, xxb, L.C);
        dist_topk_kernel<<<dim3(NPTS / 8, 8), 512, 0, stream>>>(L.xin, L.bstride, xxb, idx, L.C);
        gemm_tu_kernel<<<dim3(NPTS / 256, L.O / 16, 8), 256, 0, stream>>>(
            L.xin, L.bstride, L.W, L.g, L.b, L.m, L.v, tb, ub, L.C, L.O);
        gather_kernel<<<dim3(L.O, 2, 8), 256, 0, stream>>>(tb, ub, idx, xc + (long)L.c0 * NPTS, L.O);
    }

    w5_reduce_kernel<<<dim3(1024 / 16, 2, 8), 512, 0, stream>>>(
        xc, W5, (const float*)d_in[22], (const float*)d_in[23], (const float*)d_in[24],
        (const float*)d_in[25], pmax, psum);
    w5_combine_kernel<<<dim3(8), 256, 0, stream>>>(pmax, psum, feat);

    fc_kernel<<<dim3(512 / 4, 8), 256, 0, stream>>>(
        feat, L1, (const float*)d_in[27], (const float*)d_in[28], (const float*)d_in[29],
        (const float*)d_in[30], h1, 2048, 512, 1);
    fc_kernel<<<dim3(256 / 4, 8), 256, 0, stream>>>(
        h1, L2, (const float*)d_in[32], (const float*)d_in[33], (const float*)d_in[34],
        (const float*)d_in[35], h2, 512, 256, 1);
    fc_kernel<<<dim3(10, 8), 256, 0, stream>>>(
        h2, L3, nullptr, L3b, nullptr, nullptr, (float*)d_out, 256, 40, 0);
}

// Round 5
// 1026.168 us; speedup vs baseline: 1.4286x; 1.2544x over previous
//
#include <hip/hip_runtime.h>
#include <math.h>

#define NPTS 2048
#define KNN 20
#define EPS_BN 1e-5f

// ============================================================
// xx[b][n] = sum_c x[b][c][n]^2
// ============================================================
__global__ __launch_bounds__(256) void xx_kernel(const float* __restrict__ xin,
                                                 long bstride,
                                                 float* __restrict__ xx, int C) {
    int b = blockIdx.y;
    int n = blockIdx.x * 256 + threadIdx.x;
    const float* xb = xin + (long)b * bstride;
    float s = 0.f;
    for (int c = 0; c < C; ++c) {
        float v = xb[(long)c * NPTS + n];
        s = fmaf(v, v, s);
    }
    xx[(long)b * NPTS + n] = s;
}

// ============================================================
// Pairwise distances + exact top-k set (k=20 smallest, tie -> smaller col).
// 512 threads; block: 8 rows x 2048 cols; thread: 8 rows x 4 cols.
// Selection (per wave, owns one row): rank-based, NO dependent shuffle
// chains (round-4's 20x butterfly argmin was latency-bound at ~200us):
//   T = rank-19 of the 64 per-lane minima (>=20 values <= T guaranteed),
//   compact candidates (E[M]~24) to LDS, rank each by unique u64 key
//   (sortable float || col) via broadcast reads, emit ranks < 20.
// Output order is column-ascending, not distance-ascending: downstream
// is max over neighbors -> order-invariant.
// grid (NPTS/8, B)
// ============================================================
__global__ __launch_bounds__(512) void dist_topk_kernel(const float* __restrict__ xin,
                                                        long bstride,
                                                        const float* __restrict__ xx,
                                                        int* __restrict__ idxout, int C) {
    __shared__ float dist_s[8 * NPTS];   // 64 KB
    int b = blockIdx.y;
    int n0 = blockIdx.x * 8;
    int tid = threadIdx.x;               // 0..511
    const float* xb = xin + (long)b * bstride;

    float acc[8][4];
#pragma unroll
    for (int r = 0; r < 8; ++r)
#pragma unroll
        for (int q = 0; q < 4; ++q) acc[r][q] = 0.f;

    for (int c = 0; c < C; ++c) {
        const float* row = xb + (long)c * NPTS;
        float4 xm4 = *(const float4*)(row + 4 * tid);  // cols 4tid..4tid+3
        float xm[4] = {xm4.x, xm4.y, xm4.z, xm4.w};
#pragma unroll
        for (int r = 0; r < 8; ++r) {
            float xnv = row[n0 + r];  // block-uniform -> scalar load
#pragma unroll
            for (int q = 0; q < 4; ++q) acc[r][q] = fmaf(xnv, xm[q], acc[r][q]);
        }
    }

    const float* xxb = xx + (long)b * NPTS;
    float4 xxm4 = *(const float4*)(xxb + 4 * tid);
    float xxm[4] = {xxm4.x, xxm4.y, xxm4.z, xxm4.w};
    float xxn[8];
#pragma unroll
    for (int r = 0; r < 8; ++r) xxn[r] = xxb[n0 + r];  // uniform

#pragma unroll
    for (int r = 0; r < 8; ++r) {
        float4 d;
        d.x = xxn[r] + xxm[0] - 2.f * acc[r][0];
        d.y = xxn[r] + xxm[1] - 2.f * acc[r][1];
        d.z = xxn[r] + xxm[2] - 2.f * acc[r][2];
        d.w = xxn[r] + xxm[3] - 2.f * acc[r][3];
        *(float4*)(dist_s + r * NPTS + 4 * tid) = d;
    }
    __syncthreads();

    // -------- per-wave selection: wave w owns row n0 + w --------
    int wave = tid >> 6, lane = tid & 63;
    int n = n0 + wave;
    float v[32];
#pragma unroll
    for (int i = 0; i < 32; ++i) v[i] = dist_s[wave * NPTS + lane + 64 * i];
    int* outp = idxout + ((long)b * NPTS + n) * KNN;

    float* wls = dist_s + wave * NPTS;  // wave-private scratch (row is in regs)

    // ---- phase A: T = 20th-smallest of the 64 per-lane minima ----
    float lm = v[0];
#pragma unroll
    for (int i = 1; i < 32; ++i) lm = fminf(lm, v[i]);
    wls[lane] = lm;
    int rk = 0;
#pragma unroll
    for (int j = 0; j < 64; ++j) {
        float lj = wls[j];  // broadcast read
        rk += (lj < lm || (lj == lm && j < lane)) ? 1 : 0;
    }
    unsigned long long bm19 = __ballot(rk == 19);
    int src19 = (int)__ffsll((long long)bm19) - 1;
    float T = __shfl(lm, src19, 64);

    // ---- phase B: compact candidates (v <= T) ----
    float* cand_v = wls + 256;
    int* cand_i = (int*)(wls + 320);
    int base = 0;
#pragma unroll
    for (int i = 0; i < 32; ++i) {
        bool pred = v[i] <= T;
        unsigned long long mask = __ballot(pred);
        int prefix = __builtin_amdgcn_mbcnt_hi(
            (unsigned)(mask >> 32),
            __builtin_amdgcn_mbcnt_lo((unsigned)mask, 0));
        if (pred) {
            int pos = base + prefix;
            if (pos < 64) { cand_v[pos] = v[i]; cand_i[pos] = lane + 64 * i; }
        }
        base += (int)__popcll(mask);
    }
    int M = base;  // >= 20 guaranteed

    if (M <= 64) {
        // ---- phase C: rank candidates by unique key, emit ranks < 20 ----
        bool valid = lane < M;
        float cv = valid ? cand_v[lane] : 0.f;
        int ci = valid ? cand_i[lane] : 0;
        unsigned u = __float_as_uint(cv);
        unsigned su = (u & 0x80000000u) ? ~u : (u | 0x80000000u);  // sortable
        unsigned long long key =
            valid ? (((unsigned long long)su << 32) | (unsigned)ci) : ~0ull;
        unsigned long long* key_s = (unsigned long long*)(wls + 384);
        key_s[lane] = key;
        int rk2 = 0;
#pragma unroll
        for (int j = 0; j < 64; ++j) rk2 += (key_s[j] < key) ? 1 : 0;
        bool win = valid && (rk2 < KNN);
        unsigned long long wm = __ballot(win);
        int prefix = __builtin_amdgcn_mbcnt_hi(
            (unsigned)(wm >> 32),
            __builtin_amdgcn_mbcnt_lo((unsigned)wm, 0));
        if (win) outp[prefix] = ci;
    } else {
        // ---- fallback (P~1e-8 for continuous data): exact slow path ----
        for (int kk = 0; kk < KNN; ++kk) {
            float bv = v[0];
            int bi = 0;
#pragma unroll
            for (int i = 1; i < 32; ++i)
                if (v[i] < bv) { bv = v[i]; bi = i; }
            int bm = lane + 64 * bi;
#pragma unroll
            for (int off = 32; off >= 1; off >>= 1) {
                float ov = __shfl_xor(bv, off, 64);
                int om = __shfl_xor(bm, off, 64);
                if (ov < bv || (ov == bv && om < bm)) { bv = ov; bm = om; }
            }
            if (lane == 0) outp[kk] = bm;
#pragma unroll
            for (int i = 0; i < 32; ++i)
                if (bm == lane + 64 * i) v[i] = 3.0e38f;
        }
    }
}

// ============================================================
// t' = bn_scale*(W1-W2)@x + bn_bias ; u' = bn_scale*W2@x
// Block: 16 o x 256 n, thread: 16 o x 1 n. grid (NPTS/256, O/16, B)
// ============================================================
__global__ __launch_bounds__(256) void gemm_tu_kernel(
    const float* __restrict__ xin, long bstride, const float* __restrict__ W,
    const float* __restrict__ bg, const float* __restrict__ bb,
    const float* __restrict__ bm, const float* __restrict__ bv,
    float* __restrict__ tbuf, float* __restrict__ ubuf, int C, int O) {
    __shared__ float wa_s[128 * 16];  // (W1-W2)[c][ol]
    __shared__ float wb_s[128 * 16];  // W2[c][ol]
    int b = blockIdx.z;
    int o0 = blockIdx.y * 16;
    int n0 = blockIdx.x * 256;
    int tid = threadIdx.x;

    for (int i = tid; i < C * 16; i += 256) {
        int c = i >> 4, ol = i & 15;
        float w1 = W[(long)(o0 + ol) * (2 * C) + c];
        float w2 = W[(long)(o0 + ol) * (2 * C) + C + c];
        wa_s[i] = w1 - w2;
        wb_s[i] = w2;
    }
    __syncthreads();

    float ta[16], ua[16];
#pragma unroll
    for (int ol = 0; ol < 16; ++ol) { ta[ol] = 0.f; ua[ol] = 0.f; }

    const float* xb = xin + (long)b * bstride;
    for (int c = 0; c < C; ++c) {
        float xv = xb[(long)c * NPTS + n0 + tid];
        const float* wac = wa_s + c * 16;
        const float* wbc = wb_s + c * 16;
#pragma unroll
        for (int ol = 0; ol < 16; ++ol) {
            ta[ol] = fmaf(wac[ol], xv, ta[ol]);
            ua[ol] = fmaf(wbc[ol], xv, ua[ol]);
        }
    }

#pragma unroll
    for (int ol = 0; ol < 16; ++ol) {
        int o = o0 + ol;
        float sc = bg[o] / sqrtf(bv[o] + EPS_BN);
        float bias = bb[o] - bm[o] * sc;
        long base = ((long)b * O + o) * NPTS + n0 + tid;
        tbuf[base] = ta[ol] * sc + bias;
        ubuf[base] = ua[ol] * sc;
    }
}

// ============================================================
// out[b][o][n] = max_j lrelu(t'[b][o][n] + u'[b][o][idx[b][n][j]])
// grid (O, 2, B); block stages u' row in LDS, processes 1024 n (4/thread)
// ============================================================
__global__ __launch_bounds__(256) void gather_kernel(const float* __restrict__ tbuf,
                                                     const float* __restrict__ ubuf,
                                                     const int* __restrict__ idx,
                                                     float* __restrict__ out, int O) {
    __shared__ float urow[NPTS];
    int o = blockIdx.x, half = blockIdx.y, b = blockIdx.z;
    int tid = threadIdx.x;
    const float4* up4 = (const float4*)(ubuf + ((long)b * O + o) * NPTS);
    float4* ur4 = (float4*)urow;
    for (int i = tid; i < NPTS / 4; i += 256) ur4[i] = up4[i];
    __syncthreads();

    const float* tp = tbuf + ((long)b * O + o) * NPTS;
    float* op = out + (long)b * (512 * NPTS) + (long)o * NPTS;
    int n = half * 1024 + tid * 4;
    float4 tv4 = *(const float4*)(tp + n);
    float tv[4] = {tv4.x, tv4.y, tv4.z, tv4.w};
    float res[4];
#pragma unroll
    for (int q = 0; q < 4; ++q) {
        const int4* ip = (const int4*)(idx + ((long)b * NPTS + n + q) * KNN);
        float mx = -3.0e38f;
#pragma unroll
        for (int jj = 0; jj < 5; ++jj) {
            int4 i4 = ip[jj];
            float y0 = tv[q] + urow[i4.x];
            float y1 = tv[q] + urow[i4.y];
            float y2 = tv[q] + urow[i4.z];
            float y3 = tv[q] + urow[i4.w];
            y0 = y0 > 0.f ? y0 : 0.2f * y0;
            y1 = y1 > 0.f ? y1 : 0.2f * y1;
            y2 = y2 > 0.f ? y2 : 0.2f * y2;
            y3 = y3 > 0.f ? y3 : 0.2f * y3;
            mx = fmaxf(mx, fmaxf(fmaxf(y0, y1), fmaxf(y2, y3)));
        }
        res[q] = mx;
    }
    *(float4*)(op + n) = make_float4(res[0], res[1], res[2], res[3]);
}

// ============================================================
// emb = lrelu(bn5(W5 @ xc)); partial max/sum over n-half.
// 512 threads; thread: 16 o x 2 cols (acc[2][16]=32 regs).
// grid (1024/16, 2, B)
// ============================================================
__global__ __launch_bounds__(512) void w5_reduce_kernel(
    const float* __restrict__ xc, const float* __restrict__ W5,
    const float* __restrict__ bg, const float* __restrict__ bb,
    const float* __restrict__ bm, const float* __restrict__ bv,
    float* __restrict__ pmax, float* __restrict__ psum) {
    __shared__ float w_s[512 * 16];  // 32 KB, [c][ol]
    __shared__ float rmax[8][16];
    __shared__ float rsum[8][16];
    int b = blockIdx.z;
    int half = blockIdx.y;
    int o0 = blockIdx.x * 16;
    int tid = threadIdx.x;  // 0..511

    for (int i = tid; i < 512 * 16; i += 512) {
        int c = i >> 4, ol = i & 15;
        w_s[i] = W5[(long)(o0 + ol) * 512 + c];
    }
    __syncthreads();

    float acc[2][16];
#pragma unroll
    for (int v = 0; v < 2; ++v)
#pragma unroll
        for (int ol = 0; ol < 16; ++ol) acc[v][ol] = 0.f;

    const float* xb = xc + (long)b * 512 * NPTS + half * 1024;
    for (int c = 0; c < 512; ++c) {
        float2 xv = *(const float2*)(xb + (long)c * NPTS + 2 * tid);
        const float* wc = w_s + c * 16;
#pragma unroll
        for (int ol = 0; ol < 16; ++ol) {
            float w = wc[ol];
            acc[0][ol] = fmaf(w, xv.x, acc[0][ol]);
            acc[1][ol] = fmaf(w, xv.y, acc[1][ol]);
        }
    }

    float mx[16], sm[16];
#pragma unroll
    for (int ol = 0; ol < 16; ++ol) {
        int o = o0 + ol;
        float sc = bg[o] / sqrtf(bv[o] + EPS_BN);
        float bi = bb[o] - bm[o] * sc;
        float y0 = acc[0][ol] * sc + bi;
        float y1 = acc[1][ol] * sc + bi;
        y0 = y0 > 0.f ? y0 : 0.2f * y0;
        y1 = y1 > 0.f ? y1 : 0.2f * y1;
        mx[ol] = fmaxf(y0, y1);
        sm[ol] = y0 + y1;
    }

    int wave = tid >> 6, lane = tid & 63;
#pragma unroll
    for (int ol = 0; ol < 16; ++ol) {
        float m = mx[ol], s = sm[ol];
#pragma unroll
        for (int off = 32; off >= 1; off >>= 1) {
            m = fmaxf(m, __shfl_xor(m, off, 64));
            s += __shfl_xor(s, off, 64);
        }
        mx[ol] = m;
        sm[ol] = s;
    }
    if (lane == 0) {
#pragma unroll
        for (int ol = 0; ol < 16; ++ol) { rmax[wave][ol] = mx[ol]; rsum[wave][ol] = sm[ol]; }
    }
    __syncthreads();
    if (tid < 16) {
        float m = rmax[0][tid], s = rsum[0][tid];
#pragma unroll
        for (int w = 1; w < 8; ++w) { m = fmaxf(m, rmax[w][tid]); s += rsum[w][tid]; }
        long base = ((long)half * 8 + b) * 1024 + o0 + tid;
        pmax[base] = m;
        psum[base] = s;
    }
}

// combine halves -> feat[b][0..1023]=max, feat[b][1024..2047]=mean
__global__ __launch_bounds__(256) void w5_combine_kernel(const float* __restrict__ pmax,
                                                         const float* __restrict__ psum,
                                                         float* __restrict__ feat) {
    int b = blockIdx.x;
    for (int o = threadIdx.x; o < 1024; o += 256) {
        float m = fmaxf(pmax[(long)b * 1024 + o], pmax[(long)(8 + b) * 1024 + o]);
        float s = psum[(long)b * 1024 + o] + psum[(long)(8 + b) * 1024 + o];
        feat[(long)b * 2048 + o] = m;
        feat[(long)b * 2048 + 1024 + o] = s * (1.f / 2048.f);
    }
}

// ============================================================
// Generic FC: out[b][o] = act(bn(in[b] . W[o]))  (wave per o)
// ============================================================
__global__ __launch_bounds__(256) void fc_kernel(const float* __restrict__ in,
                                                 const float* __restrict__ W,
                                                 const float* __restrict__ bg,
                                                 const float* __restrict__ bb,
                                                 const float* __restrict__ bm,
                                                 const float* __restrict__ bv,
                                                 float* __restrict__ out, int I, int O,
                                                 int do_lrelu) {
    int b = blockIdx.y;
    int o = blockIdx.x * 4 + (threadIdx.x >> 6);
    int lane = threadIdx.x & 63;
    if (o < O) {
        const float* ip = in + (long)b * I;
        const float* wp = W + (long)o * I;
        float s = 0.f;
        for (int i = lane; i < I; i += 64) s = fmaf(ip[i], wp[i], s);
#pragma unroll
        for (int off = 32; off >= 1; off >>= 1) s += __shfl_xor(s, off, 64);
        if (lane == 0) {
            float y;
            if (bg) {
                float scv = bg[o] / sqrtf(bv[o] + EPS_BN);
                y = (s - bm[o]) * scv + bb[o];
                if (do_lrelu) y = y > 0.f ? y : 0.2f * y;
            } else {
                y = s + bb[o];
            }
            out[(long)b * O + o] = y;
        }
    }
}

// ============================================================
extern "C" void kernel_launch(void* const* d_in, const int* in_sizes, int n_in,
                              void* d_out, int out_size, void* d_ws, size_t ws_size,
                              hipStream_t stream) {
    const float* x = (const float*)d_in[0];
    const float* W1 = (const float*)d_in[1];
    const float* W2 = (const float*)d_in[6];
    const float* W3 = (const float*)d_in[11];
    const float* W4 = (const float*)d_in[16];
    const float* W5 = (const float*)d_in[21];
    const float* L1 = (const float*)d_in[26];
    const float* L2 = (const float*)d_in[31];
    const float* L3 = (const float*)d_in[36];
    const float* L3b = (const float*)d_in[37];

    // workspace layout
    float* xc = (float*)d_ws;                         // 8*512*2048
    float* tb = xc + (long)8 * 512 * NPTS;            // 8*256*2048
    float* ub = tb + (long)8 * 256 * NPTS;            // 8*256*2048
    int* idx = (int*)(ub + (long)8 * 256 * NPTS);     // 8*2048*20
    float* xxb = (float*)(idx + (long)8 * NPTS * KNN);  // 8*2048
    float* feat = xxb + (long)8 * NPTS;               // 8*2048
    float* h1 = feat + (long)8 * NPTS;                // 8*512
    float* h2 = h1 + (long)8 * 512;                   // 8*256
    // pmax/psum reuse tb region (tb/ub dead after layer-4 gather)
    float* pmax = tb;                                 // 2*8*1024
    float* psum = tb + (long)2 * 8 * 1024;            // 2*8*1024

    struct Layer {
        const float* xin; long bstride; const float* W;
        const float *g, *b, *m, *v; int C, O, c0;
    };
    Layer layers[4] = {
        {x, (long)3 * NPTS, W1,
         (const float*)d_in[2], (const float*)d_in[3], (const float*)d_in[4], (const float*)d_in[5],
         3, 64, 0},
        {xc, (long)512 * NPTS, W2,
         (const float*)d_in[7], (const float*)d_in[8], (const float*)d_in[9], (const float*)d_in[10],
         64, 64, 64},
        {xc + (long)64 * NPTS, (long)512 * NPTS, W3,
         (const float*)d_in[12], (const float*)d_in[13], (const float*)d_in[14], (const float*)d_in[15],
         64, 128, 128},
        {xc + (long)128 * NPTS, (long)512 * NPTS, W4,
         (const float*)d_in[17], (const float*)d_in[18], (const float*)d_in[19], (const float*)d_in[20],
         128, 256, 256},
    };

    for (int l = 0; l < 4; ++l) {
        const Layer& L = layers[l];
        xx_kernel<<<dim3(NPTS / 256, 8), 256, 0, stream>>>(L.xin, L.bstride, xxb, L.C);
        dist_topk_kernel<<<dim3(NPTS / 8, 8), 512, 0, stream>>>(L.xin, L.bstride, xxb, idx, L.C);
        gemm_tu_kernel<<<dim3(NPTS / 256, L.O / 16, 8), 256, 0, stream>>>(
            L.xin, L.bstride, L.W, L.g, L.b, L.m, L.v, tb, ub, L.C, L.O);
        gather_kernel<<<dim3(L.O, 2, 8), 256, 0, stream>>>(tb, ub, idx, xc + (long)L.c0 * NPTS, L.O);
    }

    w5_reduce_kernel<<<dim3(1024 / 16, 2, 8), 512, 0, stream>>>(
        xc, W5, (const float*)d_in[22], (const float*)d_in[23], (const float*)d_in[24],
        (const float*)d_in[25], pmax, psum);
    w5_combine_kernel<<<dim3(8), 256, 0, stream>>>(pmax, psum, feat);

    fc_kernel<<<dim3(512 / 4, 8), 256, 0, stream>>>(
        feat, L1, (const float*)d_in[27], (const float*)d_in[28], (const float*)d_in[29],
        (const float*)d_in[30], h1, 2048, 512, 1);
    fc_kernel<<<dim3(256 / 4, 8), 256, 0, stream>>>(
        h1, L2, (const float*)d_in[32], (const float*)d_in[33], (const float*)d_in[34],
        (const float*)d_in[35], h2, 512, 256, 1);
    fc_kernel<<<dim3(10, 8), 256, 0, stream>>>(
        h2, L3, nullptr, L3b, nullptr, nullptr, (float*)d_out, 256, 40, 0);
}

// Round 6
// 948.682 us; speedup vs baseline: 1.5453x; 1.0817x over previous
//
#include <hip/hip_runtime.h>
#include <math.h>

#define NPTS 2048
#define KNN 20
#define EPS_BN 1e-5f

typedef unsigned short ushort;
typedef __attribute__((ext_vector_type(8))) short short8;   // 8 bf16 = 4 VGPR
typedef __attribute__((ext_vector_type(4))) float float4v;  // MFMA acc

__device__ inline ushort bf16_rne(float x) {
    unsigned u = __float_as_uint(x);
    return (ushort)((u + 0x7fffu + ((u >> 16) & 1u)) >> 16);
}
__device__ inline float bf16_to_f(ushort h) {
    return __uint_as_float(((unsigned)h) << 16);
}

// ============================================================
// xx[b][n] = sum_c x[b][c][n]^2
// ============================================================
__global__ __launch_bounds__(256) void xx_kernel(const float* __restrict__ xin,
                                                 long bstride,
                                                 float* __restrict__ xx, int C) {
    int b = blockIdx.y;
    int n = blockIdx.x * 256 + threadIdx.x;
    const float* xb = xin + (long)b * bstride;
    float s = 0.f;
    for (int c = 0; c < C; ++c) {
        float v = xb[(long)c * NPTS + n];
        s = fmaf(v, v, s);
    }
    xx[(long)b * NPTS + n] = s;
}

// ============================================================
// Pairwise distances + exact top-k set (k=20 smallest, tie -> smaller col).
// 512 threads; block: 8 rows x 2048 cols; thread: 8 rows x 4 cols.
// Rank-based selection, no dependent shuffle chains. (validated round 5)
// grid (NPTS/8, B)
// ============================================================
__global__ __launch_bounds__(512) void dist_topk_kernel(const float* __restrict__ xin,
                                                        long bstride,
                                                        const float* __restrict__ xx,
                                                        int* __restrict__ idxout, int C) {
    __shared__ float dist_s[8 * NPTS];   // 64 KB
    int b = blockIdx.y;
    int n0 = blockIdx.x * 8;
    int tid = threadIdx.x;               // 0..511
    const float* xb = xin + (long)b * bstride;

    float acc[8][4];
#pragma unroll
    for (int r = 0; r < 8; ++r)
#pragma unroll
        for (int q = 0; q < 4; ++q) acc[r][q] = 0.f;

    for (int c = 0; c < C; ++c) {
        const float* row = xb + (long)c * NPTS;
        float4 xm4 = *(const float4*)(row + 4 * tid);
        float xm[4] = {xm4.x, xm4.y, xm4.z, xm4.w};
#pragma unroll
        for (int r = 0; r < 8; ++r) {
            float xnv = row[n0 + r];  // block-uniform -> scalar load
#pragma unroll
            for (int q = 0; q < 4; ++q) acc[r][q] = fmaf(xnv, xm[q], acc[r][q]);
        }
    }

    const float* xxb = xx + (long)b * NPTS;
    float4 xxm4 = *(const float4*)(xxb + 4 * tid);
    float xxm[4] = {xxm4.x, xxm4.y, xxm4.z, xxm4.w};
    float xxn[8];
#pragma unroll
    for (int r = 0; r < 8; ++r) xxn[r] = xxb[n0 + r];

#pragma unroll
    for (int r = 0; r < 8; ++r) {
        float4 d;
        d.x = xxn[r] + xxm[0] - 2.f * acc[r][0];
        d.y = xxn[r] + xxm[1] - 2.f * acc[r][1];
        d.z = xxn[r] + xxm[2] - 2.f * acc[r][2];
        d.w = xxn[r] + xxm[3] - 2.f * acc[r][3];
        *(float4*)(dist_s + r * NPTS + 4 * tid) = d;
    }
    __syncthreads();

    int wave = tid >> 6, lane = tid & 63;
    int n = n0 + wave;
    float v[32];
#pragma unroll
    for (int i = 0; i < 32; ++i) v[i] = dist_s[wave * NPTS + lane + 64 * i];
    int* outp = idxout + ((long)b * NPTS + n) * KNN;

    float* wls = dist_s + wave * NPTS;

    // phase A: T = 20th-smallest of the 64 per-lane minima
    float lm = v[0];
#pragma unroll
    for (int i = 1; i < 32; ++i) lm = fminf(lm, v[i]);
    wls[lane] = lm;
    int rk = 0;
#pragma unroll
    for (int j = 0; j < 64; ++j) {
        float lj = wls[j];
        rk += (lj < lm || (lj == lm && j < lane)) ? 1 : 0;
    }
    unsigned long long bm19 = __ballot(rk == 19);
    int src19 = (int)__ffsll((long long)bm19) - 1;
    float T = __shfl(lm, src19, 64);

    // phase B: compact candidates (v <= T)
    float* cand_v = wls + 256;
    int* cand_i = (int*)(wls + 320);
    int base = 0;
#pragma unroll
    for (int i = 0; i < 32; ++i) {
        bool pred = v[i] <= T;
        unsigned long long mask = __ballot(pred);
        int prefix = __builtin_amdgcn_mbcnt_hi(
            (unsigned)(mask >> 32),
            __builtin_amdgcn_mbcnt_lo((unsigned)mask, 0));
        if (pred) {
            int pos = base + prefix;
            if (pos < 64) { cand_v[pos] = v[i]; cand_i[pos] = lane + 64 * i; }
        }
        base += (int)__popcll(mask);
    }
    int M = base;

    if (M <= 64) {
        bool valid = lane < M;
        float cv = valid ? cand_v[lane] : 0.f;
        int ci = valid ? cand_i[lane] : 0;
        unsigned u = __float_as_uint(cv);
        unsigned su = (u & 0x80000000u) ? ~u : (u | 0x80000000u);
        unsigned long long key =
            valid ? (((unsigned long long)su << 32) | (unsigned)ci) : ~0ull;
        unsigned long long* key_s = (unsigned long long*)(wls + 384);
        key_s[lane] = key;
        int rk2 = 0;
#pragma unroll
        for (int j = 0; j < 64; ++j) rk2 += (key_s[j] < key) ? 1 : 0;
        bool win = valid && (rk2 < KNN);
        unsigned long long wm = __ballot(win);
        int prefix = __builtin_amdgcn_mbcnt_hi(
            (unsigned)(wm >> 32),
            __builtin_amdgcn_mbcnt_lo((unsigned)wm, 0));
        if (win) outp[prefix] = ci;
    } else {
        for (int kk = 0; kk < KNN; ++kk) {
            float bv = v[0];
            int bi = 0;
#pragma unroll
            for (int i = 1; i < 32; ++i)
                if (v[i] < bv) { bv = v[i]; bi = i; }
            int bm = lane + 64 * bi;
#pragma unroll
            for (int off = 32; off >= 1; off >>= 1) {
                float ov = __shfl_xor(bv, off, 64);
                int om = __shfl_xor(bm, off, 64);
                if (ov < bv || (ov == bv && om < bm)) { bv = ov; bm = om; }
            }
            if (lane == 0) outp[kk] = bm;
#pragma unroll
            for (int i = 0; i < 32; ++i)
                if (bm == lane + 64 * i) v[i] = 3.0e38f;
        }
    }
}

// ============================================================
// t' = bn_scale*(W1-W2)@x + bn_bias ; u' = bn_scale*W2@x
// ============================================================
__global__ __launch_bounds__(256) void gemm_tu_kernel(
    const float* __restrict__ xin, long bstride, const float* __restrict__ W,
    const float* __restrict__ bg, const float* __restrict__ bb,
    const float* __restrict__ bm, const float* __restrict__ bv,
    float* __restrict__ tbuf, float* __restrict__ ubuf, int C, int O) {
    __shared__ float wa_s[128 * 16];
    __shared__ float wb_s[128 * 16];
    int b = blockIdx.z;
    int o0 = blockIdx.y * 16;
    int n0 = blockIdx.x * 256;
    int tid = threadIdx.x;

    for (int i = tid; i < C * 16; i += 256) {
        int c = i >> 4, ol = i & 15;
        float w1 = W[(long)(o0 + ol) * (2 * C) + c];
        float w2 = W[(long)(o0 + ol) * (2 * C) + C + c];
        wa_s[i] = w1 - w2;
        wb_s[i] = w2;
    }
    __syncthreads();

    float ta[16], ua[16];
#pragma unroll
    for (int ol = 0; ol < 16; ++ol) { ta[ol] = 0.f; ua[ol] = 0.f; }

    const float* xb = xin + (long)b * bstride;
    for (int c = 0; c < C; ++c) {
        float xv = xb[(long)c * NPTS + n0 + tid];
        const float* wac = wa_s + c * 16;
        const float* wbc = wb_s + c * 16;
#pragma unroll
        for (int ol = 0; ol < 16; ++ol) {
            ta[ol] = fmaf(wac[ol], xv, ta[ol]);
            ua[ol] = fmaf(wbc[ol], xv, ua[ol]);
        }
    }

#pragma unroll
    for (int ol = 0; ol < 16; ++ol) {
        int o = o0 + ol;
        float sc = bg[o] / sqrtf(bv[o] + EPS_BN);
        float bias = bb[o] - bm[o] * sc;
        long base = ((long)b * O + o) * NPTS + n0 + tid;
        tbuf[base] = ta[ol] * sc + bias;
        ubuf[base] = ua[ol] * sc;
    }
}

// ============================================================
// out[b][o][n] = max_j lrelu(t'[b][o][n] + u'[b][o][idx[b][n][j]])
// ============================================================
__global__ __launch_bounds__(256) void gather_kernel(const float* __restrict__ tbuf,
                                                     const float* __restrict__ ubuf,
                                                     const int* __restrict__ idx,
                                                     float* __restrict__ out, int O) {
    __shared__ float urow[NPTS];
    int o = blockIdx.x, half = blockIdx.y, b = blockIdx.z;
    int tid = threadIdx.x;
    const float4* up4 = (const float4*)(ubuf + ((long)b * O + o) * NPTS);
    float4* ur4 = (float4*)urow;
    for (int i = tid; i < NPTS / 4; i += 256) ur4[i] = up4[i];
    __syncthreads();

    const float* tp = tbuf + ((long)b * O + o) * NPTS;
    float* op = out + (long)b * (512 * NPTS) + (long)o * NPTS;
    int n = half * 1024 + tid * 4;
    float4 tv4 = *(const float4*)(tp + n);
    float tv[4] = {tv4.x, tv4.y, tv4.z, tv4.w};
    float res[4];
#pragma unroll
    for (int q = 0; q < 4; ++q) {
        const int4* ip = (const int4*)(idx + ((long)b * NPTS + n + q) * KNN);
        float mx = -3.0e38f;
#pragma unroll
        for (int jj = 0; jj < 5; ++jj) {
            int4 i4 = ip[jj];
            float y0 = tv[q] + urow[i4.x];
            float y1 = tv[q] + urow[i4.y];
            float y2 = tv[q] + urow[i4.z];
            float y3 = tv[q] + urow[i4.w];
            y0 = y0 > 0.f ? y0 : 0.2f * y0;
            y1 = y1 > 0.f ? y1 : 0.2f * y1;
            y2 = y2 > 0.f ? y2 : 0.2f * y2;
            y3 = y3 > 0.f ? y3 : 0.2f * y3;
            mx = fmaxf(mx, fmaxf(fmaxf(y0, y1), fmaxf(y2, y3)));
        }
        res[q] = mx;
    }
    *(float4*)(op + n) = make_float4(res[0], res[1], res[2], res[3]);
}

// ============================================================
// xc fp32 [b][512][2048] -> xcT_hi/lo bf16 [b][2048][512]
// tile 32c x 256n via LDS. grid (16, 8, 8), 256 thr
// ============================================================
__global__ __launch_bounds__(256) void transpose_convert_kernel(
    const float* __restrict__ xc, ushort* __restrict__ xh, ushort* __restrict__ xl) {
    __shared__ float t[32 * 256];  // 32 KB
    int c0 = blockIdx.x * 32, n0 = blockIdx.y * 256, b = blockIdx.z;
    int tid = threadIdx.x;
#pragma unroll
    for (int i = 0; i < 8; ++i) {
        int fi = i * 256 + tid;
        int c = fi >> 6, n4 = (fi & 63) * 4;
        *(float4*)(t + c * 256 + n4) =
            *(const float4*)(xc + ((long)b * 512 + c0 + c) * NPTS + n0 + n4);
    }
    __syncthreads();
    long obase = ((long)b * NPTS + n0 + tid) * 512 + c0;
#pragma unroll
    for (int g = 0; g < 8; ++g) {
        ushort h4[4], l4[4];
#pragma unroll
        for (int j = 0; j < 4; ++j) {
            float v = t[(g * 4 + j) * 256 + tid];
            ushort h = bf16_rne(v);
            h4[j] = h;
            l4[j] = bf16_rne(v - bf16_to_f(h));
        }
        *(ushort4*)(xh + obase + g * 4) = make_ushort4(h4[0], h4[1], h4[2], h4[3]);
        *(ushort4*)(xl + obase + g * 4) = make_ushort4(l4[0], l4[1], l4[2], l4[3]);
    }
}

// ============================================================
// W5 fp32 [1024][512] -> W5h/W5l bf16 (same layout). grid(512), 256 thr
// ============================================================
__global__ __launch_bounds__(256) void w5_convert_kernel(const float* __restrict__ W5,
                                                         ushort* __restrict__ wh,
                                                         ushort* __restrict__ wl) {
    long i4 = ((long)blockIdx.x * 256 + threadIdx.x) * 4;
    float4 v = *(const float4*)(W5 + i4);
    float vv[4] = {v.x, v.y, v.z, v.w};
    ushort h4[4], l4[4];
#pragma unroll
    for (int j = 0; j < 4; ++j) {
        ushort h = bf16_rne(vv[j]);
        h4[j] = h;
        l4[j] = bf16_rne(vv[j] - bf16_to_f(h));
    }
    *(ushort4*)(wh + i4) = make_ushort4(h4[0], h4[1], h4[2], h4[3]);
    *(ushort4*)(wl + i4) = make_ushort4(l4[0], l4[1], l4[2], l4[3]);
}

// scb[o] = (scale, bias) for bn5. grid(4), 256 thr
__global__ __launch_bounds__(256) void prep_scb_kernel(const float* __restrict__ bg,
                                                       const float* __restrict__ bb,
                                                       const float* __restrict__ bm,
                                                       const float* __restrict__ bv,
                                                       float2* __restrict__ scb) {
    int o = blockIdx.x * 256 + threadIdx.x;
    float sc = bg[o] / sqrtf(bv[o] + EPS_BN);
    scb[o] = make_float2(sc, bb[o] - bm[o] * sc);
}

// ============================================================
// W5 GEMM via bf16x2 split MFMA (hi*hi + hi*lo + lo*hi), LDS-free.
// Block 256 thr = 4 waves; block tile 128o x 128n; wave tile 64x64
// (4x4 MFMA tiles, acc 16 float4). Fragments load directly from
// K-contiguous global (L2-resident). Epilogue: bn+lrelu, reduce n
// within-register + 16-lane xor-shuffle -> partial max/sum.
// grid (8 o_blk, 16 n_blk, 8 b)
// ============================================================
__global__ __launch_bounds__(256) void w5_mfma_kernel(
    const ushort* __restrict__ Wh, const ushort* __restrict__ Wl,
    const ushort* __restrict__ Xh, const ushort* __restrict__ Xl,
    const float2* __restrict__ scb, float* __restrict__ pmax,
    float* __restrict__ psum) {
    int b = blockIdx.z, nblk = blockIdx.y, oblk = blockIdx.x;
    int tid = threadIdx.x;
    int wave = tid >> 6, lane = tid & 63;
    int osub = wave & 1, nsub = wave >> 1;
    int o_base = oblk * 128 + osub * 64;
    int n_base = nblk * 128 + nsub * 64;
    int l15 = lane & 15, quad = lane >> 4;

    const ushort* Ah = Wh + (long)(o_base + l15) * 512 + quad * 8;
    const ushort* Al = Wl + (long)(o_base + l15) * 512 + quad * 8;
    const ushort* Bh = Xh + ((long)b * NPTS + n_base + l15) * 512 + quad * 8;
    const ushort* Bl = Xl + ((long)b * NPTS + n_base + l15) * 512 + quad * 8;

    float4v acc[4][4];
#pragma unroll
    for (int i = 0; i < 4; ++i)
#pragma unroll
        for (int j = 0; j < 4; ++j) acc[i][j] = (float4v)(0.f);

    for (int k = 0; k < 16; ++k) {
        int c0 = k * 32;
        short8 bh[4], bl[4];
#pragma unroll
        for (int tn = 0; tn < 4; ++tn) {
            bh[tn] = *(const short8*)(Bh + tn * (16 * 512) + c0);
            bl[tn] = *(const short8*)(Bl + tn * (16 * 512) + c0);
        }
#pragma unroll
        for (int to = 0; to < 4; ++to) {
            short8 ah = *(const short8*)(Ah + to * (16 * 512) + c0);
            short8 al = *(const short8*)(Al + to * (16 * 512) + c0);
#pragma unroll
            for (int tn = 0; tn < 4; ++tn) {
                acc[to][tn] =
                    __builtin_amdgcn_mfma_f32_16x16x32_bf16(ah, bh[tn], acc[to][tn], 0, 0, 0);
                acc[to][tn] =
                    __builtin_amdgcn_mfma_f32_16x16x32_bf16(ah, bl[tn], acc[to][tn], 0, 0, 0);
                acc[to][tn] =
                    __builtin_amdgcn_mfma_f32_16x16x32_bf16(al, bh[tn], acc[to][tn], 0, 0, 0);
            }
        }
    }

    // epilogue: D row(o) = quad*4 + reg, col(n) = l15
    int pidx = nblk * 2 + nsub;  // 0..31
#pragma unroll
    for (int to = 0; to < 4; ++to) {
        int ob = o_base + to * 16 + quad * 4;
        float mx[4], sm[4];
#pragma unroll
        for (int r = 0; r < 4; ++r) {
            float2 sb = scb[ob + r];
            float m = -3.0e38f, s = 0.f;
#pragma unroll
            for (int tn = 0; tn < 4; ++tn) {
                float y = acc[to][tn][r] * sb.x + sb.y;
                y = y > 0.f ? y : 0.2f * y;
                m = fmaxf(m, y);
                s += y;
            }
            mx[r] = m;
            sm[r] = s;
        }
#pragma unroll
        for (int r = 0; r < 4; ++r) {
#pragma unroll
            for (int off = 1; off < 16; off <<= 1) {
                mx[r] = fmaxf(mx[r], __shfl_xor(mx[r], off, 64));
                sm[r] += __shfl_xor(sm[r], off, 64);
            }
        }
        if (l15 == 0) {
            long base = ((long)pidx * 8 + b) * 1024 + ob;
#pragma unroll
            for (int r = 0; r < 4; ++r) {
                pmax[base + r] = mx[r];
                psum[base + r] = sm[r];
            }
        }
    }
}

// combine 32 partials -> feat[b][0..1023]=max, feat[b][1024..2047]=mean
__global__ __launch_bounds__(256) void w5_combine_kernel(const float* __restrict__ pmax,
                                                         const float* __restrict__ psum,
                                                         float* __restrict__ feat) {
    int b = blockIdx.x;
    for (int o = threadIdx.x; o < 1024; o += 256) {
        float m = -3.0e38f, s = 0.f;
        for (int p = 0; p < 32; ++p) {
            m = fmaxf(m, pmax[((long)p * 8 + b) * 1024 + o]);
            s += psum[((long)p * 8 + b) * 1024 + o];
        }
        feat[(long)b * 2048 + o] = m;
        feat[(long)b * 2048 + 1024 + o] = s * (1.f / 2048.f);
    }
}

// ============================================================
// Generic FC: out[b][o] = act(bn(in[b] . W[o]))  (wave per o)
// ============================================================
__global__ __launch_bounds__(256) void fc_kernel(const float* __restrict__ in,
                                                 const float* __restrict__ W,
                                                 const float* __restrict__ bg,
                                                 const float* __restrict__ bb,
                                                 const float* __restrict__ bm,
                                                 const float* __restrict__ bv,
                                                 float* __restrict__ out, int I, int O,
                                                 int do_lrelu) {
    int b = blockIdx.y;
    int o = blockIdx.x * 4 + (threadIdx.x >> 6);
    int lane = threadIdx.x & 63;
    if (o < O) {
        const float* ip = in + (long)b * I;
        const float* wp = W + (long)o * I;
        float s = 0.f;
        for (int i = lane; i < I; i += 64) s = fmaf(ip[i], wp[i], s);
#pragma unroll
        for (int off = 32; off >= 1; off >>= 1) s += __shfl_xor(s, off, 64);
        if (lane == 0) {
            float y;
            if (bg) {
                float scv = bg[o] / sqrtf(bv[o] + EPS_BN);
                y = (s - bm[o]) * scv + bb[o];
                if (do_lrelu) y = y > 0.f ? y : 0.2f * y;
            } else {
                y = s + bb[o];
            }
            out[(long)b * O + o] = y;
        }
    }
}

// ============================================================
extern "C" void kernel_launch(void* const* d_in, const int* in_sizes, int n_in,
                              void* d_out, int out_size, void* d_ws, size_t ws_size,
                              hipStream_t stream) {
    const float* x = (const float*)d_in[0];
    const float* W1 = (const float*)d_in[1];
    const float* W2 = (const float*)d_in[6];
    const float* W3 = (const float*)d_in[11];
    const float* W4 = (const float*)d_in[16];
    const float* W5 = (const float*)d_in[21];
    const float* L1 = (const float*)d_in[26];
    const float* L2 = (const float*)d_in[31];
    const float* L3 = (const float*)d_in[36];
    const float* L3b = (const float*)d_in[37];

    // workspace layout
    float* xc = (float*)d_ws;                           // 8*512*2048 f
    float* tb = xc + (long)8 * 512 * NPTS;              // 8*256*2048 f
    float* ub = tb + (long)8 * 256 * NPTS;              // 8*256*2048 f
    int* idx = (int*)(ub + (long)8 * 256 * NPTS);       // 8*2048*20 i
    float* xxb = (float*)(idx + (long)8 * NPTS * KNN);  // 8*2048 f
    float* feat = xxb + (long)8 * NPTS;                 // 8*2048 f
    float* h1 = feat + (long)8 * NPTS;                  // 8*512 f
    float* h2 = h1 + (long)8 * 512;                     // 8*256 f
    float* pmax = h2 + (long)8 * 256;                   // 32*8*1024 f
    float* psum = pmax + (long)32 * 8 * 1024;           // 32*8*1024 f
    float2* scb = (float2*)(psum + (long)32 * 8 * 1024);  // 1024 f2
    ushort* W5h = (ushort*)(scb + 1024);                // 1024*512 us
    ushort* W5l = W5h + (long)1024 * 512;               // 1024*512 us
    // xcT reuses tb/ub (dead after layer-4 gather): 8*2048*512 us each
    ushort* Xh = (ushort*)tb;
    ushort* Xl = (ushort*)ub;

    struct Layer {
        const float* xin; long bstride; const float* W;
        const float *g, *b, *m, *v; int C, O, c0;
    };
    Layer layers[4] = {
        {x, (long)3 * NPTS, W1,
         (const float*)d_in[2], (const float*)d_in[3], (const float*)d_in[4], (const float*)d_in[5],
         3, 64, 0},
        {xc, (long)512 * NPTS, W2,
         (const float*)d_in[7], (const float*)d_in[8], (const float*)d_in[9], (const float*)d_in[10],
         64, 64, 64},
        {xc + (long)64 * NPTS, (long)512 * NPTS, W3,
         (const float*)d_in[12], (const float*)d_in[13], (const float*)d_in[14], (const float*)d_in[15],
         64, 128, 128},
        {xc + (long)128 * NPTS, (long)512 * NPTS, W4,
         (const float*)d_in[17], (const float*)d_in[18], (const float*)d_in[19], (const float*)d_in[20],
         128, 256, 256},
    };

    for (int l = 0; l < 4; ++l) {
        const Layer& L = layers[l];
        xx_kernel<<<dim3(NPTS / 256, 8), 256, 0, stream>>>(L.xin, L.bstride, xxb, L.C);
        dist_topk_kernel<<<dim3(NPTS / 8, 8), 512, 0, stream>>>(L.xin, L.bstride, xxb, idx, L.C);
        gemm_tu_kernel<<<dim3(NPTS / 256, L.O / 16, 8), 256, 0, stream>>>(
            L.xin, L.bstride, L.W, L.g, L.b, L.m, L.v, tb, ub, L.C, L.O);
        gather_kernel<<<dim3(L.O, 2, 8), 256, 0, stream>>>(tb, ub, idx, xc + (long)L.c0 * NPTS, L.O);
    }

    // W5 path: convert + transpose + MFMA GEMM + combine
    w5_convert_kernel<<<dim3(512), 256, 0, stream>>>(W5, W5h, W5l);
    prep_scb_kernel<<<dim3(4), 256, 0, stream>>>(
        (const float*)d_in[22], (const float*)d_in[23], (const float*)d_in[24],
        (const float*)d_in[25], scb);
    transpose_convert_kernel<<<dim3(16, 8, 8), 256, 0, stream>>>(xc, Xh, Xl);
    w5_mfma_kernel<<<dim3(8, 16, 8), 256, 0, stream>>>(W5h, W5l, Xh, Xl, scb, pmax, psum);
    w5_combine_kernel<<<dim3(8), 256, 0, stream>>>(pmax, psum, feat);

    fc_kernel<<<dim3(512 / 4, 8), 256, 0, stream>>>(
        feat, L1, (const float*)d_in[27], (const float*)d_in[28], (const float*)d_in[29],
        (const float*)d_in[30], h1, 2048, 512, 1);
    fc_kernel<<<dim3(256 / 4, 8), 256, 0, stream>>>(
        h1, L2, (const float*)d_in[32], (const float*)d_in[33], (const float*)d_in[34],
        (const float*)d_in[35], h2, 512, 256, 1);
    fc_kernel<<<dim3(10, 8), 256, 0, stream>>>(
        h2, L3, nullptr, L3b, nullptr, nullptr, (float*)d_out, 256, 40, 0);
}